// Round 1
// baseline (124.187 us; speedup 1.0000x reference)
//
#include <hip/hip_runtime.h>
#include <math.h>

#define BB 8
#define NN 512
#define MM 512
#define HID 64

// ws layout (floats)
#define WS_MAX  0                    // 8 uint bits (atomicMax)
#define WS_CNT  8                    // 8 uint (atomicAdd)
#define WS_WN   16                   // B*N
#define WS_WM   (WS_WN + BB*NN)      // B*M
#define WS_P1   (WS_WM + BB*MM)      // B*M*3
#define WS_TOT  (WS_P1 + BB*MM*3)

__device__ __forceinline__ float wredSum(float v){
  #pragma unroll
  for (int off=32; off; off>>=1) v += __shfl_xor(v, off);
  return v;
}
__device__ __forceinline__ int wredSumI(int v){
  #pragma unroll
  for (int off=32; off; off>>=1) v += __shfl_xor(v, off);
  return v;
}
__device__ __forceinline__ float wredMax(float v){
  #pragma unroll
  for (int off=32; off; off>>=1) v = fmaxf(v, __shfl_xor(v, off));
  return v;
}

// ---------------- kernel 1: per-batch max ----------------
__global__ __launch_bounds__(256) void k_max(const float* __restrict__ sc,
                                             unsigned* __restrict__ mb){
  __shared__ float sred[4];
  int b = blockIdx.x >> 5, chunk = blockIdx.x & 31;
  const float4* p = (const float4*)(sc + (size_t)b*NN*MM) + (size_t)chunk*2048 + threadIdx.x;
  float m = 0.f;  // scores are uniform[0,1): nonnegative
  #pragma unroll
  for (int i=0;i<8;++i){
    float4 v = p[i*256];
    m = fmaxf(m, fmaxf(fmaxf(v.x,v.y), fmaxf(v.z,v.w)));
  }
  m = wredMax(m);
  if ((threadIdx.x & 63)==0) sred[threadIdx.x>>6] = m;
  __syncthreads();
  if (threadIdx.x==0){
    m = fmaxf(fmaxf(sred[0],sred[1]), fmaxf(sred[2],sred[3]));
    atomicMax(mb+b, __float_as_uint(m));  // bits-compare OK for nonneg floats
  }
}

// ---------------- kernel 2: weight-net + sufficient statistics ----------------
// grid: B*32 blocks; each block: 16 rows x 512 cols. thread t owns cols {2t, 2t+1}.
__global__ __launch_bounds__(256) void k_main(const float* __restrict__ sc,
    const float* __restrict__ pos1,
    const float* __restrict__ w1, const float* __restrict__ b1,
    const float* __restrict__ w2, const float* __restrict__ b2,
    const unsigned* __restrict__ mb,
    float* __restrict__ Wn, float* __restrict__ Wm, float* __restrict__ P1,
    unsigned* __restrict__ cnt)
{
  __shared__ float sw1[HID], sb1[HID], sw2[HID];
  __shared__ float sp1[16][3];
  __shared__ float red[64];
  int b = blockIdx.x >> 5, tile = blockIdx.x & 31;
  int n0 = tile*16, t = threadIdx.x;
  if (t < HID){ sw1[t]=w1[t]; sb1[t]=b1[t]; sw2[t]=w2[t]; }
  if (t < 48) ((float*)sp1)[t] = pos1[((size_t)b*NN + n0)*3 + t];
  __syncthreads();

  float thr = 0.1f * __uint_as_float(mb[b]);
  const float2* srow = (const float2*)(sc + ((size_t)b*NN + n0)*MM);
  float s0[16], s1[16], a0[16], a1[16];
  #pragma unroll
  for (int r=0;r<16;++r){
    float2 v = srow[r*256 + t];
    s0[r]=v.x; s1[r]=v.y; a0[r]=0.f; a1[r]=0.f;
  }
  // weight loop outer, elements inner: 3 LDS broadcast reads amortized over 64 FMA
  for (int i=0;i<HID;++i){
    float wa = sw1[i], wb = sb1[i], wc = sw2[i];
    #pragma unroll
    for (int r=0;r<16;++r){
      float h0 = fmaxf(fmaf(s0[r], wa, wb), 0.f);
      float h1 = fmaxf(fmaf(s1[r], wa, wb), 0.f);
      a0[r] = fmaf(h0, wc, a0[r]);
      a1[r] = fmaf(h1, wc, a1[r]);
    }
  }
  float bb2 = b2[0];
  int cl = 0;
  #pragma unroll
  for (int r=0;r<16;++r){
    float g0 = a0[r]+bb2, g1 = a1[r]+bb2;
    float v0 = 1.f/(1.f+__expf(-g0));
    float v1 = 1.f/(1.f+__expf(-g1));
    bool m0 = s0[r] > thr, m1 = s1[r] > thr;
    a0[r] = m0 ? v0 : 0.f;       // masked weight (unnormalized)
    a1[r] = m1 ? v1 : 0.f;
    cl += (int)m0 + (int)m1;
  }
  // accumulate column stats (private) + row sums (wave reduce)
  float wm0=0.f, wm1=0.f;
  float pa0x=0.f,pa0y=0.f,pa0z=0.f, pa1x=0.f,pa1y=0.f,pa1z=0.f;
  int lane = t & 63, wv = t >> 6;
  #pragma unroll
  for (int r=0;r<16;++r){
    wm0 += a0[r]; wm1 += a1[r];
    float x=sp1[r][0], y=sp1[r][1], z=sp1[r][2];
    pa0x = fmaf(a0[r], x, pa0x); pa0y = fmaf(a0[r], y, pa0y); pa0z = fmaf(a0[r], z, pa0z);
    pa1x = fmaf(a1[r], x, pa1x); pa1y = fmaf(a1[r], y, pa1y); pa1z = fmaf(a1[r], z, pa1z);
    float v = wredSum(a0[r] + a1[r]);
    if (!lane) red[wv*16 + r] = v;
  }
  __syncthreads();
  if (t < 16) Wn[(size_t)b*NN + n0 + t] = red[t] + red[16+t] + red[32+t] + red[48+t];
  cl = wredSumI(cl);
  if (!lane) atomicAdd(cnt + b, (unsigned)cl);
  int mbase = b*MM + 2*t;
  atomicAdd(Wm + mbase,     wm0);
  atomicAdd(Wm + mbase + 1, wm1);
  atomicAdd(P1 + (size_t)mbase*3 + 0, pa0x);
  atomicAdd(P1 + (size_t)mbase*3 + 1, pa0y);
  atomicAdd(P1 + (size_t)mbase*3 + 2, pa0z);
  atomicAdd(P1 + (size_t)(mbase+1)*3 + 0, pa1x);
  atomicAdd(P1 + (size_t)(mbase+1)*3 + 1, pa1y);
  atomicAdd(P1 + (size_t)(mbase+1)*3 + 2, pa1z);
}

// ---------------- kernel 3: centroids, H, Horn-quaternion Kabsch ----------------
__global__ __launch_bounds__(256) void k_final(
    const float* __restrict__ pos1, const float* __restrict__ pos2,
    const float* __restrict__ Wn, const float* __restrict__ Wm,
    const float* __restrict__ P1, const unsigned* __restrict__ cnt,
    float* __restrict__ out)
{
  __shared__ float sred[4];
  int b = blockIdx.x, t = threadIdx.x;
  auto bred = [&](float v)->float{
    v = wredSum(v);
    __syncthreads();
    if ((t&63)==0) sred[t>>6] = v;
    __syncthreads();
    return sred[0]+sred[1]+sred[2]+sred[3];
  };
  float Sp=0.f, c1x=0.f,c1y=0.f,c1z=0.f, c2x=0.f,c2y=0.f,c2z=0.f;
  for (int i=t; i<NN; i+=256){
    float wn = Wn[b*NN+i];
    const float* p1 = pos1 + ((size_t)b*NN+i)*3;
    Sp += wn;
    c1x = fmaf(wn,p1[0],c1x); c1y = fmaf(wn,p1[1],c1y); c1z = fmaf(wn,p1[2],c1z);
    float wm = Wm[b*MM+i];
    const float* p2 = pos2 + ((size_t)b*MM+i)*3;
    c2x = fmaf(wm,p2[0],c2x); c2y = fmaf(wm,p2[1],c2y); c2z = fmaf(wm,p2[2],c2z);
  }
  float S = bred(Sp) + 1e-8f;
  float inv = 1.f/S;
  c1x = bred(c1x)*inv; c1y = bred(c1y)*inv; c1z = bred(c1z)*inv;
  c2x = bred(c2x)*inv; c2y = bred(c2y)*inv; c2z = bred(c2z)*inv;

  float H[9] = {0,0,0,0,0,0,0,0,0};
  for (int m=t; m<MM; m+=256){
    float wmn = Wm[b*MM+m]*inv;
    const float* pp = P1 + ((size_t)b*MM+m)*3;
    float ax = pp[0]*inv - wmn*c1x;
    float ay = pp[1]*inv - wmn*c1y;
    float az = pp[2]*inv - wmn*c1z;
    const float* p2 = pos2 + ((size_t)b*MM+m)*3;
    float qx = p2[0]-c2x, qy = p2[1]-c2y, qz = p2[2]-c2z;
    H[0]=fmaf(ax,qx,H[0]); H[1]=fmaf(ax,qy,H[1]); H[2]=fmaf(ax,qz,H[2]);
    H[3]=fmaf(ay,qx,H[3]); H[4]=fmaf(ay,qy,H[4]); H[5]=fmaf(ay,qz,H[5]);
    H[6]=fmaf(az,qx,H[6]); H[7]=fmaf(az,qy,H[7]); H[8]=fmaf(az,qz,H[8]);
  }
  #pragma unroll
  for (int k=0;k<9;++k) H[k] = bred(H[k]);

  if (t==0){
    float Sxx=H[0],Sxy=H[1],Sxz=H[2];
    float Syx=H[3],Syy=H[4],Syz=H[5];
    float Szx=H[6],Szy=H[7],Szz=H[8];
    // Horn's 4x4 K-matrix for M = sum w * p1c p2c^T (= H); max eigvec q: p2 ~= R(q) p1
    float Kq[4][4];
    Kq[0][0]=Sxx+Syy+Szz; Kq[0][1]=Syz-Szy;     Kq[0][2]=Szx-Sxz;     Kq[0][3]=Sxy-Syx;
    Kq[1][0]=Kq[0][1];    Kq[1][1]=Sxx-Syy-Szz; Kq[1][2]=Sxy+Syx;     Kq[1][3]=Szx+Sxz;
    Kq[2][0]=Kq[0][2];    Kq[2][1]=Kq[1][2];    Kq[2][2]=Syy-Sxx-Szz; Kq[2][3]=Syz+Szy;
    Kq[3][0]=Kq[0][3];    Kq[3][1]=Kq[1][3];    Kq[3][2]=Kq[2][3];    Kq[3][3]=Szz-Sxx-Syy;
    // shift to PSD (Frobenius norm >= |lambda|max), then normalize
    float fn=0.f;
    #pragma unroll
    for (int i=0;i<4;++i){
      #pragma unroll
      for (int j=0;j<4;++j) fn += Kq[i][j]*Kq[i][j];
    }
    float sig = sqrtf(fn) + 1e-30f;
    #pragma unroll
    for (int i=0;i<4;++i) Kq[i][i] += sig;
    fn=0.f;
    #pragma unroll
    for (int i=0;i<4;++i){
      #pragma unroll
      for (int j=0;j<4;++j) fn += Kq[i][j]*Kq[i][j];
    }
    float nsc = rsqrtf(fn + 1e-38f);
    #pragma unroll
    for (int i=0;i<4;++i){
      #pragma unroll
      for (int j=0;j<4;++j) Kq[i][j] *= nsc;
    }
    // 4 Frobenius-normalized squarings -> K^16, then 16 power iters -> K^256
    #pragma unroll
    for (int sqi=0; sqi<4; ++sqi){
      float Bq[4][4]; float f2=0.f;
      #pragma unroll
      for (int i=0;i<4;++i){
        #pragma unroll
        for (int j=0;j<4;++j){
          float v=0.f;
          #pragma unroll
          for (int k=0;k<4;++k) v = fmaf(Kq[i][k],Kq[k][j],v);
          Bq[i][j]=v; f2 += v*v;
        }
      }
      float isc = rsqrtf(f2 + 1e-38f);
      #pragma unroll
      for (int i=0;i<4;++i){
        #pragma unroll
        for (int j=0;j<4;++j) Kq[i][j] = Bq[i][j]*isc;
      }
    }
    float q0=1.f, q1=0.31f, q2=0.67f, q3=0.93f;
    #pragma unroll
    for (int it=0; it<16; ++it){
      float n0 = Kq[0][0]*q0+Kq[0][1]*q1+Kq[0][2]*q2+Kq[0][3]*q3;
      float n1 = Kq[1][0]*q0+Kq[1][1]*q1+Kq[1][2]*q2+Kq[1][3]*q3;
      float n2 = Kq[2][0]*q0+Kq[2][1]*q1+Kq[2][2]*q2+Kq[2][3]*q3;
      float n3 = Kq[3][0]*q0+Kq[3][1]*q1+Kq[3][2]*q2+Kq[3][3]*q3;
      float nn = rsqrtf(n0*n0+n1*n1+n2*n2+n3*n3 + 1e-38f);
      q0=n0*nn; q1=n1*nn; q2=n2*nn; q3=n3*nn;
    }
    float R00=q0*q0+q1*q1-q2*q2-q3*q3, R01=2.f*(q1*q2-q0*q3),          R02=2.f*(q1*q3+q0*q2);
    float R10=2.f*(q1*q2+q0*q3),       R11=q0*q0-q1*q1+q2*q2-q3*q3,    R12=2.f*(q2*q3-q0*q1);
    float R20=2.f*(q1*q3-q0*q2),       R21=2.f*(q2*q3+q0*q1),          R22=q0*q0-q1*q1-q2*q2+q3*q3;
    float tx = c2x - (R00*c1x + R01*c1y + R02*c1z);
    float ty = c2y - (R10*c1x + R11*c1y + R12*c1z);
    float tz = c2z - (R20*c1x + R21*c1y + R22*c1z);
    float tn = sqrtf(tx*tx+ty*ty+tz*tz);
    float itn = 1.f/fmaxf(tn, 1e-12f);
    tx*=itn; ty*=itn; tz*=itn;
    if (cnt[b] < 5u){
      R00=1.f;R01=0.f;R02=0.f; R10=0.f;R11=1.f;R12=0.f; R20=0.f;R21=0.f;R22=1.f;
      tx=0.f; ty=0.f; tz=1.f;
    }
    float* Ro = out + b*9;
    Ro[0]=R00;Ro[1]=R01;Ro[2]=R02;Ro[3]=R10;Ro[4]=R11;Ro[5]=R12;Ro[6]=R20;Ro[7]=R21;Ro[8]=R22;
    float* to = out + BB*9 + b*3;
    to[0]=tx; to[1]=ty; to[2]=tz;
  }
}

extern "C" void kernel_launch(void* const* d_in, const int* in_sizes, int n_in,
                              void* d_out, int out_size, void* d_ws, size_t ws_size,
                              hipStream_t stream){
  const float* pos1 = (const float*)d_in[0];
  const float* pos2 = (const float*)d_in[1];
  const float* sc   = (const float*)d_in[2];
  // d_in[3] = K (unused by reference)
  const float* w1   = (const float*)d_in[4];
  const float* b1   = (const float*)d_in[5];
  const float* w2   = (const float*)d_in[6];
  const float* b2   = (const float*)d_in[7];
  float* ws = (float*)d_ws;
  unsigned* mbp = (unsigned*)(ws + WS_MAX);
  unsigned* cnt = (unsigned*)(ws + WS_CNT);
  float* Wn = ws + WS_WN;
  float* Wm = ws + WS_WM;
  float* P1 = ws + WS_P1;

  hipMemsetAsync(d_ws, 0, (size_t)WS_TOT*sizeof(float), stream);
  k_max  <<<dim3(BB*32), dim3(256), 0, stream>>>(sc, mbp);
  k_main <<<dim3(BB*32), dim3(256), 0, stream>>>(sc, pos1, w1, b1, w2, b2, mbp, Wn, Wm, P1, cnt);
  k_final<<<dim3(BB),    dim3(256), 0, stream>>>(pos1, pos2, Wn, Wm, P1, cnt, (float*)d_out);
}